// Round 7
// baseline (862.086 us; speedup 1.0000x reference)
//
#include <hip/hip_runtime.h>
#include <hip/hip_bf16.h>

typedef __hip_bfloat16 bf16;
typedef __attribute__((ext_vector_type(8))) short bf16x8;
typedef __attribute__((ext_vector_type(4))) float f32x4;

// Problem constants (B,N,C,H,D) = (64,1024,64,64,16), CHEB_K=3
constexpr int Bn = 64;
constexpr int Nn = 1024;
constexpr int Dd = 16;
constexpr int Cc = 64;
constexpr int Hh = 64;
constexpr int CI = 128;   // C+H
constexpr int OG = 128;   // 2H (gate out)
constexpr int OU = 64;    // H  (update out)
constexpr int Jt = Bn * CI;  // 8192 "feature rows" for the agg GEMM

__device__ __forceinline__ float b2f(bf16 v) { return __bfloat162float(v); }
__device__ __forceinline__ float lo2f(unsigned u) { return __uint_as_float(u << 16); }
__device__ __forceinline__ float hi2f(unsigned u) { return __uint_as_float(u & 0xffff0000u); }
__device__ __forceinline__ float bfbits2f(unsigned short u) { return __uint_as_float(((unsigned)u) << 16); }
__device__ __forceinline__ unsigned short f2bfbits(float x) {
    bf16 h = __float2bfloat16(x);
    return *reinterpret_cast<unsigned short*>(&h);
}
__device__ __forceinline__ float rfl(float x) {
    return __int_as_float(__builtin_amdgcn_readfirstlane(__float_as_int(x)));
}

// dtype-flagged scalar load (flag==1 -> bf16, 0 -> f32)
__device__ __forceinline__ float ldin(const void* p, size_t i, int flag) {
    return flag ? b2f(((const bf16*)p)[i]) : ((const float*)p)[i];
}

__device__ __forceinline__ void gload_lds16(const void* g, void* l) {
    __builtin_amdgcn_global_load_lds((const __attribute__((address_space(1))) void*)g,
                                     (__attribute__((address_space(3))) void*)l, 16, 0, 0);
}

// ---------------------------------------------------------------- dtype detect
__global__ void detect_kernel(const void* glnw, int* flag) {
    unsigned u = *(const unsigned*)glnw;
    *flag = (u == 0x3F800000u) ? 0 : 1;
}

// ---------------------------------------------------------------- input -> f32 conversion (biases)
__global__ void conv_f32(const void* __restrict__ src, float* __restrict__ dst,
                         int n, const int* __restrict__ flag) {
    const int f = *flag;
    for (int i = blockIdx.x * blockDim.x + threadIdx.x; i < n; i += gridDim.x * blockDim.x)
        dst[i] = ldin(src, i, f);
}

// ---------------------------------------------------------------- W[d=16][k=384][O] -> Wt[dh=2][O][k=384][d8] bf16
// One 16B block of Wt = 8 d-values for one (o,k).  grid (24 ktiles of 16, 2 dh)
__global__ __launch_bounds__(256) void wtrans2(const void* __restrict__ src, unsigned short* __restrict__ Wt,
                                               int O, int osh, const int* __restrict__ flag) {
    const int f = *flag;
    const int k0 = blockIdx.x * 16;
    const int dh = blockIdx.y;
    __shared__ unsigned short tile[8 * 16 * 128];   // [dl][kk][o], up to 32KB
    const int t = threadIdx.x;
    const int total = 128 * O;
    for (int idx = t; idx < total; idx += 256) {
        const int o = idx & (O - 1);
        const int r = idx >> osh;
        const int kk = r & 15, dl = r >> 4;
        tile[idx] = f2bfbits(ldin(src, ((size_t)(dh * 8 + dl) * 384 + k0 + kk) * O + o, f));
    }
    __syncthreads();
    for (int u = t; u < 16 * O; u += 256) {
        const int o = u >> 4, kk = u & 15;
        unsigned short o8[8];
#pragma unroll
        for (int dl = 0; dl < 8; dl++) o8[dl] = tile[(dl * 16 + kk) * O + o];
        *(uint4*)&Wt[((size_t)(dh * O + o) * 384 + k0 + kk) * 8] = *(const uint4*)o8;
    }
}

// ---------------------------------------------------------------- LayerNorm(node_emb + time_emb)
__global__ void ln_kernel(const void* __restrict__ nemb, const void* __restrict__ temb,
                          const void* __restrict__ wg, const void* __restrict__ bg,
                          const void* __restrict__ wu, const void* __restrict__ bu,
                          float* __restrict__ e_g, float* __restrict__ e_u,
                          const int* __restrict__ flag) {
    const int f = *flag;
    int t = blockIdx.x * blockDim.x + threadIdx.x;
    if (t >= 2 * Nn) return;
    int which = t >> 10;
    int n = t & (Nn - 1);
    float v[Dd];
    float mean = 0.f;
#pragma unroll
    for (int d = 0; d < Dd; d++) { v[d] = ldin(nemb, n * Dd + d, f) + ldin(temb, d, f); mean += v[d]; }
    mean *= (1.f / Dd);
    float var = 0.f;
#pragma unroll
    for (int d = 0; d < Dd; d++) { float c = v[d] - mean; var += c * c; }
    var *= (1.f / Dd);
    float inv = 1.f / sqrtf(var + 1e-12f);
    const void* w = which ? wu : wg;
    const void* bb = which ? bu : bg;
    float* e = which ? e_u : e_g;
#pragma unroll
    for (int d = 0; d < Dd; d++)
        e[n * Dd + d] = (v[d] - mean) * inv * ldin(w, d, f) + ldin(bb, d, f);
}

// ---------------------------------------------------------------- A = softmax(e e^T, axis=1) -> bf16
__global__ __launch_bounds__(256) void attn_kernel(const float* __restrict__ e, bf16* __restrict__ A) {
    __shared__ float en[Dd];
    __shared__ float logits[Nn];
    __shared__ float red[256];
    const int n = blockIdx.x, t = threadIdx.x;
    if (t < Dd) en[t] = e[n * Dd + t];
    __syncthreads();
    float lmax = -1e30f;
    for (int m = t; m < Nn; m += 256) {
        float s = 0.f;
#pragma unroll
        for (int d = 0; d < Dd; d++) s += en[d] * e[m * Dd + d];
        logits[m] = s;
        lmax = fmaxf(lmax, s);
    }
    red[t] = lmax; __syncthreads();
    for (int s = 128; s > 0; s >>= 1) { if (t < s) red[t] = fmaxf(red[t], red[t + s]); __syncthreads(); }
    const float M = red[0];
    __syncthreads();
    float lsum = 0.f;
    for (int m = t; m < Nn; m += 256) { float p = expf(logits[m] - M); logits[m] = p; lsum += p; }
    red[t] = lsum; __syncthreads();
    for (int s = 128; s > 0; s >>= 1) { if (t < s) red[t] += red[t + s]; __syncthreads(); }
    const float inv = 1.f / red[0];
    for (int m = t; m < Nn; m += 256) A[(size_t)n * Nn + m] = __float2bfloat16(logits[m] * inv);
}

// ---------------------------------------------------------------- build xg0 in BOTH layouts
__global__ __launch_bounds__(256) void build_xg0(const void* __restrict__ x, const void* __restrict__ oth,
                                                 bf16* __restrict__ xg0t, bf16* __restrict__ xg0s,
                                                 const int* __restrict__ flag, int oth_bf16) {
    const int f = *flag;
    const int b = blockIdx.x;           // 64
    const int n0 = blockIdx.y * 64;     // 16
    __shared__ bf16 tile[128][68];
    const int t = threadIdx.x;
#pragma unroll
    for (int idx = t; idx < 64 * 128; idx += 256) {
        const int n = idx >> 7, i = idx & 127;  // contiguous over i
        const size_t base = ((size_t)b << 10) + n0 + n;
        float v;
        if (i < Cc) v = ldin(x, base * Cc + i, f);
        else v = oth_bf16 ? b2f(((const bf16*)oth)[base * Hh + i - Cc])
                          : ldin(oth, base * Hh + i - Cc, f);
        tile[i][n] = __float2bfloat16(v);
        xg0s[base * CI + i] = tile[i][n];
    }
    __syncthreads();
#pragma unroll
    for (int idx = t; idx < 128 * 64; idx += 256) {
        const int i = idx >> 6, n = idx & 63;   // contiguous over n
        xg0t[((size_t)(b * CI + i) << 10) + n0 + n] = tile[i][n];
    }
}

// ---------------------------------------------------------------- MFMA agg
// A: (N,N) bf16 row-major. X/Sub: (Jt, N) bf16 (j-major, node-minor).
// cheb=0: C = A@X ; cheb=1: C = 2*A@X - Sub
// write_t: also write Ct in [j][n] layout.  Cs always written coalesced in [b][n][i] layout.
__global__ __launch_bounds__(256) void agg_mfma(const bf16* __restrict__ Amat,
                                                const bf16* __restrict__ Xmat,
                                                const bf16* __restrict__ Sub,
                                                bf16* __restrict__ Ct,
                                                bf16* __restrict__ Cs,
                                                int cheb, int write_t) {
    __shared__ bf16 Atile[128 * 32];
    __shared__ bf16 Xtile[128 * 32];
    __shared__ unsigned short Ts[128 * 136];   // [m-local][i] padded (272B rows, 16B aligned)
    char* AtileC = (char*)Atile;
    char* XtileC = (char*)Xtile;

    const int t = threadIdx.x;
    const int lane = t & 63, w = t >> 6;
    const int j0 = blockIdx.x * 128;           // j0 = b*128 -> one b per block
    const int m0 = blockIdx.y * 128;
    const int wr = (w >> 1) * 64, wc = (w & 1) * 64;
    const int lr = lane & 15, lq = lane >> 4;

    f32x4 acc[4][4];
#pragma unroll
    for (int a = 0; a < 4; a++)
#pragma unroll
        for (int b = 0; b < 4; b++) acc[a][b] = (f32x4){0.f, 0.f, 0.f, 0.f};

    const int srow = w * 16 + (lane >> 2);
    const int scb = (lane & 3) * 16;

    for (int k0 = 0; k0 < Nn; k0 += 32) {
        __syncthreads();
#pragma unroll
        for (int p = 0; p < 2; p++) {
            const int row = p * 64 + srow;
            gload_lds16((const char*)Amat + (size_t)(m0 + row) * 2048 + k0 * 2 + scb,
                        AtileC + p * 4096 + w * 1024);
            gload_lds16((const char*)Xmat + (size_t)(j0 + row) * 2048 + k0 * 2 + scb,
                        XtileC + p * 4096 + w * 1024);
        }
        __syncthreads();
        bf16x8 af[4], xf[4];
#pragma unroll
        for (int fr = 0; fr < 4; fr++)
            af[fr] = *(const bf16x8*)(AtileC + (wr + fr * 16 + lr) * 64 + lq * 16);
#pragma unroll
        for (int fc = 0; fc < 4; fc++)
            xf[fc] = *(const bf16x8*)(XtileC + (wc + fc * 16 + lr) * 64 + lq * 16);
#pragma unroll
        for (int fr = 0; fr < 4; fr++)
#pragma unroll
            for (int fc = 0; fc < 4; fc++)
                acc[fr][fc] = __builtin_amdgcn_mfma_f32_16x16x32_bf16(af[fr], xf[fc], acc[fr][fc], 0, 0, 0);
    }

#pragma unroll
    for (int fr = 0; fr < 4; fr++) {
        const int ml = wr + fr * 16 + lq * 4;       // m-local, 4 consecutive
        const int m = m0 + ml;
#pragma unroll
        for (int fc = 0; fc < 4; fc++) {
            const int i = wc + fc * 16 + lr;        // feature index within b
            const int j = j0 + i;
            f32x4 v = acc[fr][fc];
            const size_t off = ((size_t)j << 10) + m;
            if (cheb) {
                const ushort4 s = *(const ushort4*)((const unsigned short*)Sub + off);
                v.x = 2.f * v.x - bfbits2f(s.x);
                v.y = 2.f * v.y - bfbits2f(s.y);
                v.z = 2.f * v.z - bfbits2f(s.z);
                v.w = 2.f * v.w - bfbits2f(s.w);
            }
            ushort4 o4;
            o4.x = f2bfbits(v.x); o4.y = f2bfbits(v.y); o4.z = f2bfbits(v.z); o4.w = f2bfbits(v.w);
            if (write_t) *(ushort4*)((unsigned short*)Ct + off) = o4;
            const unsigned short* pv = (const unsigned short*)&o4;
#pragma unroll
            for (int q = 0; q < 4; q++) Ts[(ml + q) * 136 + i] = pv[q];
        }
    }
    __syncthreads();
    // coalesced write-out of Cs[b][m0..+128][0..128]
    const int b = j0 >> 7;
#pragma unroll
    for (int p = 0; p < 8; p++) {
        const int u = p * 256 + t;
        const int m = u >> 4, ig = (u & 15) * 8;
        const uint4 val = *(const uint4*)&Ts[m * 136 + ig];
        *(uint4*)((unsigned short*)Cs + (((size_t)b << 10) + m0 + m) * 128 + ig) = val;
    }
}

// ---------------------------------------------------------------- per-node MFMA GEMM, pipelined
// G nodes/block, o-range 64 (one 16-o subtile per wave). 24 phases = (ch3 x ks4 x dh2),
// ONE barrier per phase, double-buffered W (2x32KB) and X (2x G*4KB): DMA(w+1) issued after the
// barrier protecting phase w, overlaps phase-w mix compute, drained by next barrier (m97 pattern).
// Wt layout [dh][O][k384][d8]: one 16B block = 8 d-values for (o,k); mix reads are XOR-dispersed
// via the DMA *source* index (dest must stay linear: wave-uniform base + lane*16).
template<int G, int GATE>
__global__ __launch_bounds__(256) void pernode_gemm(
    const bf16* __restrict__ x0, const bf16* __restrict__ x1, const bf16* __restrict__ x2,
    const float* __restrict__ e, const unsigned short* __restrict__ Wt,
    const float* __restrict__ bpool,
    const void* __restrict__ state, const float* __restrict__ r_in,
    bf16* __restrict__ zs, float* __restrict__ r_out, void* __restrict__ out,
    const int* __restrict__ flag)
{
    constexpr int OSTR = GATE ? 128 : 64;
    const int f = *flag;
    const int bx = blockIdx.x;
    const int grp = GATE ? (bx >> 1) : bx;
    const int obase = GATE ? ((bx & 1) << 6) : 0;
    const int n0 = grp * G;

    __shared__ bf16 Wb[2][16384];        // 2 x 32KB: [o64][k-slot32][d8], slots XOR'd by (o&7)
    __shared__ bf16 Xb[2][G * 2048];     // 2 x G*4KB: [node][b64][k32]
    const int t = threadIdx.x;
    const int lane = t & 63, w = t >> 6;
    const int lr = lane & 15, lq = lane >> 4;
    const int og = obase + w * 16 + lr;  // this lane's output column

    // e coefficients, wave-uniform (SGPRs)
    float en[G][16];
#pragma unroll
    for (int nl = 0; nl < G; nl++)
#pragma unroll
        for (int d = 0; d < 16; d++) en[nl][d] = rfl(e[(n0 + nl) * 16 + d]);

    f32x4 acc[G][4];
#pragma unroll
    for (int nl = 0; nl < G; nl++)
#pragma unroll
        for (int mt = 0; mt < 4; mt++) acc[nl][mt] = (f32x4){0.f, 0.f, 0.f, 0.f};

    const bf16* xs[3] = {x0, x1, x2};

    // ---- DMA issuers (no barriers inside) ----
    auto issueW = [&](int wph, int buf) {
        const int ch = wph >> 3, ks = (wph >> 1) & 3, dh = wph & 1;
        char* dst = (char*)Wb[buf];
#pragma unroll
        for (int p = 0; p < 8; p++) {
            const int u = p * 256 + t;
            const int o = u >> 5;
            const int kk = (u & 31) ^ (o & 7);     // source-side XOR swizzle
            gload_lds16(Wt + ((size_t)(dh * OSTR + obase + o) * 384 + ch * 128 + ks * 32 + kk) * 8,
                        dst + u * 16);
        }
    };
    auto issueX = [&](int s, int buf) {
        const int ch = s >> 2, ks = s & 3;
        const bf16* Xsrc = xs[ch];
        char* dst = (char*)Xb[buf];
#pragma unroll
        for (int p = 0; p < G; p++) {
            const int u = p * 256 + t;
            const int r = u >> 2, kg = u & 3;      // r = nl*64 + b
            const int nl = r >> 6, b = r & 63;
            gload_lds16(Xsrc + (((size_t)b << 10) + n0 + nl) * 128 + ks * 32 + kg * 8,
                        dst + u * 16);
        }
    };

    issueW(0, 0);
    issueX(0, 0);

    float wacc[G][8];
#pragma unroll 1
    for (int wph = 0; wph < 24; wph++) {
        const int s = wph >> 1, dh = wph & 1;
        __syncthreads();                            // drains DMA(wph) (+protects buffer reuse)
        if (wph + 1 < 24) issueW(wph + 1, (wph + 1) & 1);
        if (dh == 0 && s + 1 < 12) issueX(s + 1, (s + 1) & 1);

        if (dh == 0) {
#pragma unroll
            for (int nl = 0; nl < G; nl++)
#pragma unroll
                for (int j = 0; j < 8; j++) wacc[nl][j] = 0.f;
        }
        // mix this d-half: lane reads 8 blocks (o = w*16+lr, k = lq*8+j)
        const char* wsrc = (const char*)Wb[wph & 1];
#pragma unroll
        for (int j = 0; j < 8; j++) {
            const int slot = (lq * 8 + j) ^ (lr & 7);   // matches source swizzle (o&7 == lr&7)
            const bf16x8 wv = *(const bf16x8*)(wsrc + ((w * 16 + lr) * 32 + slot) * 16);
            const unsigned* wu = (const unsigned*)&wv;
            float v[8];
            v[0] = lo2f(wu[0]); v[1] = hi2f(wu[0]);
            v[2] = lo2f(wu[1]); v[3] = hi2f(wu[1]);
            v[4] = lo2f(wu[2]); v[5] = hi2f(wu[2]);
            v[6] = lo2f(wu[3]); v[7] = hi2f(wu[3]);
#pragma unroll
            for (int nl = 0; nl < G; nl++) {
                float s8 = 0.f;
#pragma unroll
                for (int dl = 0; dl < 8; dl++) s8 += en[nl][dh * 8 + dl] * v[dl];
                wacc[nl][j] += s8;
            }
        }

        if (dh == 1) {
            const char* xsrc = (const char*)Xb[s & 1];
#pragma unroll
            for (int nl = 0; nl < G; nl++) {
                union U8 { bf16x8 v; unsigned short s[8]; } bh, bl;
#pragma unroll
                for (int j = 0; j < 8; j++) {
                    const unsigned short h = f2bfbits(wacc[nl][j]);
                    bh.s[j] = h;
                    bl.s[j] = f2bfbits(wacc[nl][j] - bfbits2f(h));
                }
#pragma unroll
                for (int mt = 0; mt < 4; mt++) {
                    const bf16x8 af = *(const bf16x8*)(xsrc + (nl * 64 + mt * 16 + lr) * 64 + lq * 16);
                    acc[nl][mt] = __builtin_amdgcn_mfma_f32_16x16x32_bf16(af, bh.v, acc[nl][mt], 0, 0, 0);
                    acc[nl][mt] = __builtin_amdgcn_mfma_f32_16x16x32_bf16(af, bl.v, acc[nl][mt], 0, 0, 0);
                }
            }
        }
    }

    // epilogue
    const int ol = og & 63;
#pragma unroll
    for (int nl = 0; nl < G; nl++) {
        const int n_ = n0 + nl;
        float bias = 0.f;
#pragma unroll
        for (int d = 0; d < 16; d++) bias += en[nl][d] * bpool[d * OSTR + og];
#pragma unroll
        for (int mt = 0; mt < 4; mt++) {
            const f32x4 a = acc[nl][mt];
#pragma unroll
            for (int q = 0; q < 4; q++) {
                const int b = mt * 16 + lq * 4 + q;
                const size_t idx = (((size_t)b << 10) + n_) * 64 + ol;
                const float v = a[q] + bias;
                if (GATE) {
                    const float sg = 1.f / (1.f + expf(-v));
                    if (obase == 0) {
                        const float st = ldin(state, idx, f);
                        zs[idx] = __float2bfloat16(sg * st);   // z * state
                    } else {
                        r_out[idx] = sg;                        // r
                    }
                } else {
                    const float hc = tanhf(v);
                    const float r = r_in[idx];
                    const float st = ldin(state, idx, f);
                    const float o = r * st + (1.f - r) * hc;
                    if (f) ((bf16*)out)[idx] = __float2bfloat16(o);
                    else   ((float*)out)[idx] = o;
                }
            }
        }
    }
}

extern "C" void kernel_launch(void* const* d_in, const int* in_sizes, int n_in,
                              void* d_out, int out_size, void* d_ws, size_t ws_size,
                              hipStream_t stream) {
    const void* x     = d_in[0];
    const void* state = d_in[2];
    const void* nemb  = d_in[3];
    const void* temb  = d_in[5];
    const void* gW    = d_in[6];
    const void* gb    = d_in[7];
    const void* glnw  = d_in[8];
    const void* glnb  = d_in[9];
    const void* uW    = d_in[10];
    const void* ub    = d_in[11];
    const void* ulnw  = d_in[12];
    const void* ulnb  = d_in[13];

    constexpr int GW_N = Dd * 3 * CI * OG;   // 786432
    constexpr int GB_N = Dd * OG;            // 2048
    constexpr int UW_N = Dd * 3 * CI * OU;   // 393216
    constexpr int UB_N = Dd * OU;            // 1024

    char* base = (char*)d_ws;
    size_t off = 0;
    auto carve = [&](size_t bytes) { char* p = base + off; off += (bytes + 255) & ~(size_t)255; return p; };
    int*   flag = (int*)carve(4);
    unsigned short* gWt = (unsigned short*)carve(GW_N * 2);   // [dh][o=128][k=384][d8] bf16
    unsigned short* uWt = (unsigned short*)carve(UW_N * 2);   // [dh][o=64][k=384][d8]  bf16
    float* gbf = (float*)carve(GB_N * 4);
    float* ubf = (float*)carve(UB_N * 4);
    float* e_g = (float*)carve(Nn * Dd * 4);
    float* e_u = (float*)carve(Nn * Dd * 4);
    bf16*  Abf  = (bf16*)carve((size_t)Nn * Nn * 2);
    bf16*  xg0t = (bf16*)carve((size_t)Jt * Nn * 2);
    bf16*  xg0s = (bf16*)carve((size_t)Jt * Nn * 2);
    bf16*  xg1t = (bf16*)carve((size_t)Jt * Nn * 2);
    bf16*  xg1s = (bf16*)carve((size_t)Jt * Nn * 2);
    bf16*  xg2s = (bf16*)carve((size_t)Jt * Nn * 2);
    bf16*  zs   = (bf16*)carve((size_t)Bn * Nn * Hh * 2);
    float* r_s  = (float*)carve((size_t)Bn * Nn * Hh * 4);
    if (ws_size < off) return;  // fail visibly rather than corrupt

    detect_kernel<<<1, 1, 0, stream>>>(glnw, flag);
    wtrans2<<<dim3(24, 2), 256, 0, stream>>>(gW, gWt, OG, 7, flag);
    wtrans2<<<dim3(24, 2), 256, 0, stream>>>(uW, uWt, OU, 6, flag);
    conv_f32<<<(GB_N + 255) / 256, 256, 0, stream>>>(gb, gbf, GB_N, flag);
    conv_f32<<<(UB_N + 255) / 256, 256, 0, stream>>>(ub, ubf, UB_N, flag);
    ln_kernel<<<8, 256, 0, stream>>>(nemb, temb, glnw, glnb, ulnw, ulnb, e_g, e_u, flag);

    // ---- gate magcn ----
    attn_kernel<<<Nn, 256, 0, stream>>>(e_g, Abf);
    build_xg0<<<dim3(Bn, 16), 256, 0, stream>>>(x, state, xg0t, xg0s, flag, 0);
    agg_mfma<<<dim3(Jt / 128, Nn / 128), 256, 0, stream>>>(Abf, xg0t, nullptr, xg1t, xg1s, 0, 1);
    agg_mfma<<<dim3(Jt / 128, Nn / 128), 256, 0, stream>>>(Abf, xg1t, xg0t, xg1t, xg2s, 1, 0);
    pernode_gemm<4, 1><<<512, 256, 0, stream>>>(xg0s, xg1s, xg2s, e_g, gWt, gbf,
                                                state, nullptr, zs, r_s, nullptr, flag);

    // ---- update magcn ----
    attn_kernel<<<Nn, 256, 0, stream>>>(e_u, Abf);
    build_xg0<<<dim3(Bn, 16), 256, 0, stream>>>(x, zs, xg0t, xg0s, flag, 1);
    agg_mfma<<<dim3(Jt / 128, Nn / 128), 256, 0, stream>>>(Abf, xg0t, nullptr, xg1t, xg1s, 0, 1);
    agg_mfma<<<dim3(Jt / 128, Nn / 128), 256, 0, stream>>>(Abf, xg1t, xg0t, xg1t, xg2s, 1, 0);
    pernode_gemm<2, 0><<<512, 256, 0, stream>>>(xg0s, xg1s, xg2s, e_u, uWt, ubf,
                                                state, r_s, nullptr, nullptr, d_out, flag);
}

// Round 8
// 466.210 us; speedup vs baseline: 1.8491x; 1.8491x over previous
//
#include <hip/hip_runtime.h>
#include <hip/hip_bf16.h>

typedef __hip_bfloat16 bf16;
typedef __attribute__((ext_vector_type(8))) short bf16x8;
typedef __attribute__((ext_vector_type(4))) float f32x4;

// Problem constants (B,N,C,H,D) = (64,1024,64,64,16), CHEB_K=3
constexpr int Bn = 64;
constexpr int Nn = 1024;
constexpr int Dd = 16;
constexpr int Cc = 64;
constexpr int Hh = 64;
constexpr int CI = 128;   // C+H
constexpr int OG = 128;   // 2H (gate out)
constexpr int OU = 64;    // H  (update out)
constexpr int Jt = Bn * CI;  // 8192 "feature rows" for the agg GEMM

__device__ __forceinline__ float b2f(bf16 v) { return __bfloat162float(v); }
__device__ __forceinline__ float lo2f(unsigned u) { return __uint_as_float(u << 16); }
__device__ __forceinline__ float hi2f(unsigned u) { return __uint_as_float(u & 0xffff0000u); }
__device__ __forceinline__ float bfbits2f(unsigned short u) { return __uint_as_float(((unsigned)u) << 16); }
__device__ __forceinline__ unsigned short f2bfbits(float x) {
    bf16 h = __float2bfloat16(x);
    return *reinterpret_cast<unsigned short*>(&h);
}
__device__ __forceinline__ float rfl(float x) {
    return __int_as_float(__builtin_amdgcn_readfirstlane(__float_as_int(x)));
}

// dtype-flagged scalar load (flag==1 -> bf16, 0 -> f32)
__device__ __forceinline__ float ldin(const void* p, size_t i, int flag) {
    return flag ? b2f(((const bf16*)p)[i]) : ((const float*)p)[i];
}

__device__ __forceinline__ void gload_lds16(const void* g, void* l) {
    __builtin_amdgcn_global_load_lds((const __attribute__((address_space(1))) void*)g,
                                     (__attribute__((address_space(3))) void*)l, 16, 0, 0);
}

// ---------------------------------------------------------------- dtype detect
__global__ void detect_kernel(const void* glnw, int* flag) {
    unsigned u = *(const unsigned*)glnw;
    *flag = (u == 0x3F800000u) ? 0 : 1;
}

// ---------------------------------------------------------------- input -> f32 conversion (biases)
__global__ void conv_f32(const void* __restrict__ src, float* __restrict__ dst,
                         int n, const int* __restrict__ flag) {
    const int f = *flag;
    for (int i = blockIdx.x * blockDim.x + threadIdx.x; i < n; i += gridDim.x * blockDim.x)
        dst[i] = ldin(src, i, f);
}

// ---------------------------------------------------------------- W[d][k=384][O] -> Wt[d][O][k=384] bf16
__global__ __launch_bounds__(256) void wtrans(const void* __restrict__ src, unsigned short* __restrict__ Wt,
                                              int O, int osh, const int* __restrict__ flag) {
    const int f = *flag;
    const int k0 = blockIdx.x * 64;
    const int d = blockIdx.y;
    __shared__ unsigned short tile[64][136];
    const int t = threadIdx.x;
    for (int idx = t; idx < 64 * O; idx += 256) {
        const int kk = idx >> osh, o = idx & (O - 1);
        tile[kk][o] = f2bfbits(ldin(src, ((size_t)d * 384 + k0 + kk) * O + o, f));
    }
    __syncthreads();
    for (int idx = t; idx < O * 64; idx += 256) {
        const int o = idx >> 6, kk = idx & 63;
        Wt[((size_t)d * O + o) * 384 + k0 + kk] = tile[kk][o];
    }
}

// ---------------------------------------------------------------- LayerNorm(node_emb + time_emb)
__global__ void ln_kernel(const void* __restrict__ nemb, const void* __restrict__ temb,
                          const void* __restrict__ wg, const void* __restrict__ bg,
                          const void* __restrict__ wu, const void* __restrict__ bu,
                          float* __restrict__ e_g, float* __restrict__ e_u,
                          const int* __restrict__ flag) {
    const int f = *flag;
    int t = blockIdx.x * blockDim.x + threadIdx.x;
    if (t >= 2 * Nn) return;
    int which = t >> 10;
    int n = t & (Nn - 1);
    float v[Dd];
    float mean = 0.f;
#pragma unroll
    for (int d = 0; d < Dd; d++) { v[d] = ldin(nemb, n * Dd + d, f) + ldin(temb, d, f); mean += v[d]; }
    mean *= (1.f / Dd);
    float var = 0.f;
#pragma unroll
    for (int d = 0; d < Dd; d++) { float c = v[d] - mean; var += c * c; }
    var *= (1.f / Dd);
    float inv = 1.f / sqrtf(var + 1e-12f);
    const void* w = which ? wu : wg;
    const void* bb = which ? bu : bg;
    float* e = which ? e_u : e_g;
#pragma unroll
    for (int d = 0; d < Dd; d++)
        e[n * Dd + d] = (v[d] - mean) * inv * ldin(w, d, f) + ldin(bb, d, f);
}

// ---------------------------------------------------------------- A = softmax(e e^T, axis=1) -> bf16
__global__ __launch_bounds__(256) void attn_kernel(const float* __restrict__ e, bf16* __restrict__ A) {
    __shared__ float en[Dd];
    __shared__ float logits[Nn];
    __shared__ float red[256];
    const int n = blockIdx.x, t = threadIdx.x;
    if (t < Dd) en[t] = e[n * Dd + t];
    __syncthreads();
    float lmax = -1e30f;
    for (int m = t; m < Nn; m += 256) {
        float s = 0.f;
#pragma unroll
        for (int d = 0; d < Dd; d++) s += en[d] * e[m * Dd + d];
        logits[m] = s;
        lmax = fmaxf(lmax, s);
    }
    red[t] = lmax; __syncthreads();
    for (int s = 128; s > 0; s >>= 1) { if (t < s) red[t] = fmaxf(red[t], red[t + s]); __syncthreads(); }
    const float M = red[0];
    __syncthreads();
    float lsum = 0.f;
    for (int m = t; m < Nn; m += 256) { float p = expf(logits[m] - M); logits[m] = p; lsum += p; }
    red[t] = lsum; __syncthreads();
    for (int s = 128; s > 0; s >>= 1) { if (t < s) red[t] += red[t + s]; __syncthreads(); }
    const float inv = 1.f / red[0];
    for (int m = t; m < Nn; m += 256) A[(size_t)n * Nn + m] = __float2bfloat16(logits[m] * inv);
}

// ---------------------------------------------------------------- build xg0 in BOTH layouts
__global__ __launch_bounds__(256) void build_xg0(const void* __restrict__ x, const void* __restrict__ oth,
                                                 bf16* __restrict__ xg0t, bf16* __restrict__ xg0s,
                                                 const int* __restrict__ flag, int oth_bf16) {
    const int f = *flag;
    const int b = blockIdx.x;           // 64
    const int n0 = blockIdx.y * 64;     // 16
    __shared__ bf16 tile[128][68];
    const int t = threadIdx.x;
#pragma unroll
    for (int idx = t; idx < 64 * 128; idx += 256) {
        const int n = idx >> 7, i = idx & 127;  // contiguous over i
        const size_t base = ((size_t)b << 10) + n0 + n;
        float v;
        if (i < Cc) v = ldin(x, base * Cc + i, f);
        else v = oth_bf16 ? b2f(((const bf16*)oth)[base * Hh + i - Cc])
                          : ldin(oth, base * Hh + i - Cc, f);
        tile[i][n] = __float2bfloat16(v);
        xg0s[base * CI + i] = tile[i][n];
    }
    __syncthreads();
#pragma unroll
    for (int idx = t; idx < 128 * 64; idx += 256) {
        const int i = idx >> 6, n = idx & 63;   // contiguous over n
        xg0t[((size_t)(b * CI + i) << 10) + n0 + n] = tile[i][n];
    }
}

// ---------------------------------------------------------------- MFMA agg  (unchanged from r6)
__global__ __launch_bounds__(256) void agg_mfma(const bf16* __restrict__ Amat,
                                                const bf16* __restrict__ Xmat,
                                                const bf16* __restrict__ Sub,
                                                bf16* __restrict__ Ct,
                                                bf16* __restrict__ Cs,
                                                int cheb, int write_t) {
    __shared__ bf16 Atile[128 * 32];
    __shared__ bf16 Xtile[128 * 32];
    __shared__ unsigned short Ts[128 * 136];   // [m-local][i] padded
    char* AtileC = (char*)Atile;
    char* XtileC = (char*)Xtile;

    const int t = threadIdx.x;
    const int lane = t & 63, w = t >> 6;
    const int j0 = blockIdx.x * 128;           // j0 = b*128 -> one b per block
    const int m0 = blockIdx.y * 128;
    const int wr = (w >> 1) * 64, wc = (w & 1) * 64;
    const int lr = lane & 15, lq = lane >> 4;

    f32x4 acc[4][4];
#pragma unroll
    for (int a = 0; a < 4; a++)
#pragma unroll
        for (int b = 0; b < 4; b++) acc[a][b] = (f32x4){0.f, 0.f, 0.f, 0.f};

    const int srow = w * 16 + (lane >> 2);
    const int scb = (lane & 3) * 16;

    for (int k0 = 0; k0 < Nn; k0 += 32) {
        __syncthreads();
#pragma unroll
        for (int p = 0; p < 2; p++) {
            const int row = p * 64 + srow;
            gload_lds16((const char*)Amat + (size_t)(m0 + row) * 2048 + k0 * 2 + scb,
                        AtileC + p * 4096 + w * 1024);
            gload_lds16((const char*)Xmat + (size_t)(j0 + row) * 2048 + k0 * 2 + scb,
                        XtileC + p * 4096 + w * 1024);
        }
        __syncthreads();
        bf16x8 af[4], xf[4];
#pragma unroll
        for (int fr = 0; fr < 4; fr++)
            af[fr] = *(const bf16x8*)(AtileC + (wr + fr * 16 + lr) * 64 + lq * 16);
#pragma unroll
        for (int fc = 0; fc < 4; fc++)
            xf[fc] = *(const bf16x8*)(XtileC + (wc + fc * 16 + lr) * 64 + lq * 16);
#pragma unroll
        for (int fr = 0; fr < 4; fr++)
#pragma unroll
            for (int fc = 0; fc < 4; fc++)
                acc[fr][fc] = __builtin_amdgcn_mfma_f32_16x16x32_bf16(af[fr], xf[fc], acc[fr][fc], 0, 0, 0);
    }

#pragma unroll
    for (int fr = 0; fr < 4; fr++) {
        const int ml = wr + fr * 16 + lq * 4;
        const int m = m0 + ml;
#pragma unroll
        for (int fc = 0; fc < 4; fc++) {
            const int i = wc + fc * 16 + lr;
            const int j = j0 + i;
            f32x4 v = acc[fr][fc];
            const size_t off = ((size_t)j << 10) + m;
            if (cheb) {
                const ushort4 s = *(const ushort4*)((const unsigned short*)Sub + off);
                v.x = 2.f * v.x - bfbits2f(s.x);
                v.y = 2.f * v.y - bfbits2f(s.y);
                v.z = 2.f * v.z - bfbits2f(s.z);
                v.w = 2.f * v.w - bfbits2f(s.w);
            }
            ushort4 o4;
            o4.x = f2bfbits(v.x); o4.y = f2bfbits(v.y); o4.z = f2bfbits(v.z); o4.w = f2bfbits(v.w);
            if (write_t) *(ushort4*)((unsigned short*)Ct + off) = o4;
            const unsigned short* pv = (const unsigned short*)&o4;
#pragma unroll
            for (int q = 0; q < 4; q++) Ts[(ml + q) * 136 + i] = pv[q];
        }
    }
    __syncthreads();
    const int b = j0 >> 7;
#pragma unroll
    for (int p = 0; p < 8; p++) {
        const int u = p * 256 + t;
        const int m = u >> 4, ig = (u & 15) * 8;
        const uint4 val = *(const uint4*)&Ts[m * 136 + ig];
        *(uint4*)((unsigned short*)Cs + (((size_t)b << 10) + m0 + m) * 128 + ig) = val;
    }
}

// ---------------------------------------------------------------- per-node MFMA GEMM, r6 layouts +
// single-barrier pipeline: 24 phases (ch3 x ks4 x dh2), W double-buffered (2x32KB, [d8][o64][k32]
// 64B rows — the proven near-conflict-free pattern), X single-buffered. After barrier p we issue
// W(p+1) (and X(s) on even p); the DMA flies across phase-p mix compute, drained by barrier p+1.
template<int G, int GATE>
__global__ __launch_bounds__(256) void pernode_gemm(
    const bf16* __restrict__ x0, const bf16* __restrict__ x1, const bf16* __restrict__ x2,
    const float* __restrict__ e, const unsigned short* __restrict__ Wt,
    const float* __restrict__ bpool,
    const void* __restrict__ state, const float* __restrict__ r_in,
    bf16* __restrict__ zs, float* __restrict__ r_out, void* __restrict__ out,
    const int* __restrict__ flag)
{
    constexpr int OSTR = GATE ? 128 : 64;
    const int f = *flag;
    const int bx = blockIdx.x;
    const int grp = GATE ? (bx >> 1) : bx;
    const int obase = GATE ? ((bx & 1) << 6) : 0;
    const int n0 = grp * G;

    __shared__ bf16 Wb[2][8 * 64 * 32];  // 2 x 32KB: [d8][o64][k32], 64B rows
    __shared__ bf16 Xl[G * 64 * 32];     // G*4KB: [node][b64][k32], 64B rows
    char* XlC = (char*)Xl;

    const int t = threadIdx.x;
    const int lane = t & 63, w = t >> 6;
    const int lr = lane & 15, lq = lane >> 4;
    const int og = obase + w * 16 + lr;  // this lane's output column

    // e coefficients, wave-uniform (SGPRs)
    float en[G][16];
#pragma unroll
    for (int nl = 0; nl < G; nl++)
#pragma unroll
        for (int d = 0; d < 16; d++) en[nl][d] = rfl(e[(n0 + nl) * 16 + d]);

    f32x4 acc[G][4];
#pragma unroll
    for (int nl = 0; nl < G; nl++)
#pragma unroll
        for (int mt = 0; mt < 4; mt++) acc[nl][mt] = (f32x4){0.f, 0.f, 0.f, 0.f};

    const bf16* xs[3] = {x0, x1, x2};

    auto issueW = [&](int p) {           // into Wb[p&1]
        const int ch = p >> 3, ks = (p >> 1) & 3, dh = p & 1;
        char* dst = (char*)Wb[p & 1];
#pragma unroll
        for (int pp = 0; pp < 8; pp++) {
            const int u = pp * 256 + t;
            const int r = u >> 2, kg = u & 3;     // r = d*64 + ol
            const int d = r >> 6, ol = r & 63;
            gload_lds16(Wt + ((size_t)((dh * 8 + d) * OSTR + obase + ol) * 384)
                           + ch * 128 + ks * 32 + kg * 8,
                        dst + u * 16);
        }
    };
    auto issueX = [&](int s) {
        const int ch = s >> 2, ks = s & 3;
        const bf16* Xsrc = xs[ch];
#pragma unroll
        for (int pp = 0; pp < G; pp++) {
            const int u = pp * 256 + t;
            const int r = u >> 2, kg = u & 3;     // r = nl*64 + b
            const int nl = r >> 6, b = r & 63;
            gload_lds16(Xsrc + (((size_t)b << 10) + n0 + nl) * 128 + ks * 32 + kg * 8,
                        XlC + u * 16);
        }
    };

    issueW(0);

    float wacc[G][8];
#pragma unroll 1
    for (int p = 0; p < 24; p++) {
        const int s = p >> 1, dh = p & 1;
        __syncthreads();                 // drains W(p) [+ X(s) when p odd]; protects buffer reuse
        if (dh == 0) issueX(s);          // consumed by MFMA at end of phase p+1
        if (p + 1 < 24) issueW(p + 1);

        const char* wsrc = (const char*)Wb[p & 1];
        if (dh == 0) {
#pragma unroll
            for (int nl = 0; nl < G; nl++)
#pragma unroll
                for (int j = 0; j < 8; j++) wacc[nl][j] = 0.f;
#pragma unroll
            for (int d = 0; d < 8; d++) {
                const bf16x8 wv = *(const bf16x8*)(wsrc + (d * 64 + w * 16 + lr) * 64 + lq * 16);
                const unsigned* wu = (const unsigned*)&wv;
                float v[8];
                v[0] = lo2f(wu[0]); v[1] = hi2f(wu[0]);
                v[2] = lo2f(wu[1]); v[3] = hi2f(wu[1]);
                v[4] = lo2f(wu[2]); v[5] = hi2f(wu[2]);
                v[6] = lo2f(wu[3]); v[7] = hi2f(wu[3]);
#pragma unroll
                for (int nl = 0; nl < G; nl++) {
                    const float ed = en[nl][d];
#pragma unroll
                    for (int j = 0; j < 8; j++) wacc[nl][j] += ed * v[j];
                }
            }
        } else {
#pragma unroll
            for (int d = 0; d < 8; d++) {
                const bf16x8 wv = *(const bf16x8*)(wsrc + (d * 64 + w * 16 + lr) * 64 + lq * 16);
                const unsigned* wu = (const unsigned*)&wv;
                float v[8];
                v[0] = lo2f(wu[0]); v[1] = hi2f(wu[0]);
                v[2] = lo2f(wu[1]); v[3] = hi2f(wu[1]);
                v[4] = lo2f(wu[2]); v[5] = hi2f(wu[2]);
                v[6] = lo2f(wu[3]); v[7] = hi2f(wu[3]);
#pragma unroll
                for (int nl = 0; nl < G; nl++) {
                    const float ed = en[nl][8 + d];
#pragma unroll
                    for (int j = 0; j < 8; j++) wacc[nl][j] += ed * v[j];
                }
            }
            // hi/lo split + MFMA (X(s) drained by this phase's barrier)
#pragma unroll
            for (int nl = 0; nl < G; nl++) {
                union U8 { bf16x8 v; unsigned short s[8]; } bh, bl;
#pragma unroll
                for (int j = 0; j < 8; j++) {
                    const unsigned short h = f2bfbits(wacc[nl][j]);
                    bh.s[j] = h;
                    bl.s[j] = f2bfbits(wacc[nl][j] - bfbits2f(h));
                }
#pragma unroll
                for (int mt = 0; mt < 4; mt++) {
                    const bf16x8 af = *(const bf16x8*)(XlC + (nl * 64 + mt * 16 + lr) * 64 + lq * 16);
                    acc[nl][mt] = __builtin_amdgcn_mfma_f32_16x16x32_bf16(af, bh.v, acc[nl][mt], 0, 0, 0);
                    acc[nl][mt] = __builtin_amdgcn_mfma_f32_16x16x32_bf16(af, bl.v, acc[nl][mt], 0, 0, 0);
                }
            }
        }
    }

    // epilogue
    const int ol = og & 63;
#pragma unroll
    for (int nl = 0; nl < G; nl++) {
        const int n_ = n0 + nl;
        float bias = 0.f;
#pragma unroll
        for (int d = 0; d < 16; d++) bias += en[nl][d] * bpool[d * OSTR + og];
#pragma unroll
        for (int mt = 0; mt < 4; mt++) {
            const f32x4 a = acc[nl][mt];
#pragma unroll
            for (int q = 0; q < 4; q++) {
                const int b = mt * 16 + lq * 4 + q;
                const size_t idx = (((size_t)b << 10) + n_) * 64 + ol;
                const float v = a[q] + bias;
                if (GATE) {
                    const float sg = 1.f / (1.f + expf(-v));
                    if (obase == 0) {
                        const float st = ldin(state, idx, f);
                        zs[idx] = __float2bfloat16(sg * st);   // z * state
                    } else {
                        r_out[idx] = sg;                        // r
                    }
                } else {
                    const float hc = tanhf(v);
                    const float r = r_in[idx];
                    const float st = ldin(state, idx, f);
                    const float o = r * st + (1.f - r) * hc;
                    if (f) ((bf16*)out)[idx] = __float2bfloat16(o);
                    else   ((float*)out)[idx] = o;
                }
            }
        }
    }
}

extern "C" void kernel_launch(void* const* d_in, const int* in_sizes, int n_in,
                              void* d_out, int out_size, void* d_ws, size_t ws_size,
                              hipStream_t stream) {
    const void* x     = d_in[0];
    const void* state = d_in[2];
    const void* nemb  = d_in[3];
    const void* temb  = d_in[5];
    const void* gW    = d_in[6];
    const void* gb    = d_in[7];
    const void* glnw  = d_in[8];
    const void* glnb  = d_in[9];
    const void* uW    = d_in[10];
    const void* ub    = d_in[11];
    const void* ulnw  = d_in[12];
    const void* ulnb  = d_in[13];

    constexpr int GW_N = Dd * 3 * CI * OG;   // 786432
    constexpr int GB_N = Dd * OG;            // 2048
    constexpr int UW_N = Dd * 3 * CI * OU;   // 393216
    constexpr int UB_N = Dd * OU;            // 1024

    char* base = (char*)d_ws;
    size_t off = 0;
    auto carve = [&](size_t bytes) { char* p = base + off; off += (bytes + 255) & ~(size_t)255; return p; };
    int*   flag = (int*)carve(4);
    unsigned short* gWt = (unsigned short*)carve(GW_N * 2);   // [d][o=128][k=384] bf16
    unsigned short* uWt = (unsigned short*)carve(UW_N * 2);   // [d][o=64][k=384]  bf16
    float* gbf = (float*)carve(GB_N * 4);
    float* ubf = (float*)carve(UB_N * 4);
    float* e_g = (float*)carve(Nn * Dd * 4);
    float* e_u = (float*)carve(Nn * Dd * 4);
    bf16*  Abf  = (bf16*)carve((size_t)Nn * Nn * 2);
    bf16*  xg0t = (bf16*)carve((size_t)Jt * Nn * 2);
    bf16*  xg0s = (bf16*)carve((size_t)Jt * Nn * 2);
    bf16*  xg1t = (bf16*)carve((size_t)Jt * Nn * 2);
    bf16*  xg1s = (bf16*)carve((size_t)Jt * Nn * 2);
    bf16*  xg2s = (bf16*)carve((size_t)Jt * Nn * 2);
    bf16*  zs   = (bf16*)carve((size_t)Bn * Nn * Hh * 2);
    float* r_s  = (float*)carve((size_t)Bn * Nn * Hh * 4);
    if (ws_size < off) return;  // fail visibly rather than corrupt

    detect_kernel<<<1, 1, 0, stream>>>(glnw, flag);
    wtrans<<<dim3(6, 16), 256, 0, stream>>>(gW, gWt, OG, 7, flag);
    wtrans<<<dim3(6, 16), 256, 0, stream>>>(uW, uWt, OU, 6, flag);
    conv_f32<<<(GB_N + 255) / 256, 256, 0, stream>>>(gb, gbf, GB_N, flag);
    conv_f32<<<(UB_N + 255) / 256, 256, 0, stream>>>(ub, ubf, UB_N, flag);
    ln_kernel<<<8, 256, 0, stream>>>(nemb, temb, glnw, glnb, ulnw, ulnb, e_g, e_u, flag);

    // ---- gate magcn ----
    attn_kernel<<<Nn, 256, 0, stream>>>(e_g, Abf);
    build_xg0<<<dim3(Bn, 16), 256, 0, stream>>>(x, state, xg0t, xg0s, flag, 0);
    agg_mfma<<<dim3(Jt / 128, Nn / 128), 256, 0, stream>>>(Abf, xg0t, nullptr, xg1t, xg1s, 0, 1);
    agg_mfma<<<dim3(Jt / 128, Nn / 128), 256, 0, stream>>>(Abf, xg1t, xg0t, xg1t, xg2s, 1, 0);
    pernode_gemm<4, 1><<<512, 256, 0, stream>>>(xg0s, xg1s, xg2s, e_g, gWt, gbf,
                                                state, nullptr, zs, r_s, nullptr, flag);

    // ---- update magcn ----
    attn_kernel<<<Nn, 256, 0, stream>>>(e_u, Abf);
    build_xg0<<<dim3(Bn, 16), 256, 0, stream>>>(x, zs, xg0t, xg0s, flag, 1);
    agg_mfma<<<dim3(Jt / 128, Nn / 128), 256, 0, stream>>>(Abf, xg0t, nullptr, xg1t, xg1s, 0, 1);
    agg_mfma<<<dim3(Jt / 128, Nn / 128), 256, 0, stream>>>(Abf, xg1t, xg0t, xg1t, xg2s, 1, 0);
    pernode_gemm<2, 0><<<512, 256, 0, stream>>>(xg0s, xg1s, xg2s, e_u, uWt, ubf,
                                                state, r_s, nullptr, nullptr, d_out, flag);
}